// Round 16
// baseline (18.929 us; speedup 1.0000x reference)
//
#include <hip/hip_runtime.h>
#include <hip/hip_bf16.h>

#define NQ 6
#define DIM 64
#define NLAYERS 6

typedef __attribute__((ext_vector_type(8))) short bf16x8;
typedef __attribute__((ext_vector_type(4))) float f32x4;

// ---------------------------------------------------------------------------
// build_M: fused circuit matrix M = P*U5*...*P*U0*F (complex 64x64), emitted
// as MFMA fragments, single bf16 plane per component:
//   frag f = (jt*2 + chunk)*2 + plane  (0 = real, 1 = imag)
//   ushort addr = f*512 + lane16*8 + e          (16 KB total image)
//   lane16 = (j&15) + 16*((k>>3)&3), chunk = k>>5, e = k&7, jt = j>>4.
// HW trig; M bf16-rounding -> ~2e-4 on probs (validated R10+). ~0.4 us (R14).
// ---------------------------------------------------------------------------
__global__ __launch_bounds__(64) void build_M(const float* __restrict__ w,
                                              unsigned short* __restrict__ Bf) {
    const int k = blockIdx.x;    // column 0..63
    const int j = threadIdx.x;   // row/lane 0..63

    int t = (j * k) & 63;
    float sv, cv;
    __sincosf((float)t * (3.14159265358979f / 32.0f), &sv, &cv);  // exp(i*pi*t/32)
    float vr = cv * 0.125f;
    float vi = sv * 0.125f;

    int m = j;
#pragma unroll
    for (int q = 0; q < NQ; ++q) {
        int cb = 5 - q;
        int tb = 5 - ((q + 1) % NQ);
        if ((m >> cb) & 1) m ^= (1 << tb);
    }
    const int dst4 = m << 2;

#pragma unroll
    for (int l = 0; l < NLAYERS; ++l) {
#pragma unroll
        for (int q = 0; q < NQ; ++q) {
            float th = w[l * NQ + q] * 0.5f;
            float c = __cosf(th), s = __sinf(th);
            int b = 5 - q;
            float pr = __shfl_xor(vr, 1 << b);
            float pi = __shfl_xor(vi, 1 << b);
            float sgn = ((j >> b) & 1) ? s : -s;
            vr = c * vr + sgn * pr;
            vi = c * vi + sgn * pi;
        }
        vr = __int_as_float(__builtin_amdgcn_ds_permute(dst4, __float_as_int(vr)));
        vi = __int_as_float(__builtin_amdgcn_ds_permute(dst4, __float_as_int(vi)));
    }

    const int jt = j >> 4;
    const int lane16 = (j & 15) + 16 * ((k >> 3) & 3);
    const int chunk = k >> 5;
    const int e = k & 7;
    const int base = ((jt * 2 + chunk) * 2) * 512 + lane16 * 8 + e;

    __hip_bfloat16 rh = __float2bfloat16(vr);
    __hip_bfloat16 ih = __float2bfloat16(vi);
    Bf[base]       = *(unsigned short*)&rh;
    Bf[base + 512] = *(unsigned short*)&ih;
}

// ---------------------------------------------------------------------------
// qenc_main: NO LDS, NO barrier. Each lane preloads its full 256B M-slice
// (16 fragments -> 64 VGPRs) + its x slice as one 20-load burst, then runs
// the MFMA loop register-only. Waves are fully independent -> staggered
// retirement overlaps the x-read and out-write streams. 1024 blocks x 256
// thr = 16 waves/CU at <=128 VGPR (launch_bounds(256,4)).
// ---------------------------------------------------------------------------
__global__ __launch_bounds__(256, 4) void qenc_main(const float* __restrict__ x,
                                                    const unsigned short* __restrict__ Bf,
                                                    float* __restrict__ out) {
    const int tid = threadIdx.x;
    const int lane = tid & 63;
    const int wid = tid >> 6;
    const int row0 = blockIdx.x * 64 + wid * 16;
    const int r = lane & 15;      // batch row within tile
    const int g = lane >> 4;      // k-group

    // ---- preload M: 16 fragments x 16B per lane (frag f at bb[f*64])
    const bf16x8* bb = (const bf16x8*)Bf + lane;
    bf16x8 mfr[8], mfi[8];        // [jt*2 + c]
#pragma unroll
    for (int f = 0; f < 8; ++f) {
        mfr[f] = bb[(f * 2 + 0) * 64];
        mfi[f] = bb[(f * 2 + 1) * 64];
    }

    // ---- x loads (same burst)
    const float* xp = x + (size_t)(row0 + r) * DIM + 8 * g;
    float xf[16];
    *(float4*)(xf)      = *(const float4*)(xp);
    *(float4*)(xf + 4)  = *(const float4*)(xp + 4);
    *(float4*)(xf + 8)  = *(const float4*)(xp + 32);
    *(float4*)(xf + 12) = *(const float4*)(xp + 36);

    // ---- norm (reduce over the 4 lanes sharing row r)
    float n0 = 0.f;
#pragma unroll
    for (int i = 0; i < 16; ++i) n0 = fmaf(xf[i], xf[i], n0);
    n0 += __shfl_xor(n0, 16);
    n0 += __shfl_xor(n0, 32);
    const float inv = 1.0f / n0;

    // ---- hi/lo bf16 x-fragments (chunk c: k = 32c + 8g .. +7)
    bf16x8 xh[2], xl[2];
#pragma unroll
    for (int c = 0; c < 2; ++c)
#pragma unroll
        for (int i = 0; i < 8; ++i) {
            float f = xf[c * 8 + i];
            __hip_bfloat16 hh = __float2bfloat16(f);
            __hip_bfloat16 ll = __float2bfloat16(f - __bfloat162float(hh));
            xh[c][i] = *(short*)&hh;
            xl[c][i] = *(short*)&ll;
        }

    // ---- MFMA loop: all operands in registers
    const f32x4 z = {0.f, 0.f, 0.f, 0.f};
    f32x4 acr[4] = {z, z, z, z};
    f32x4 aci[4] = {z, z, z, z};
#pragma unroll
    for (int jt = 0; jt < 4; ++jt) {
#pragma unroll
        for (int c = 0; c < 2; ++c) {
            const int f = jt * 2 + c;
            acr[jt] = __builtin_amdgcn_mfma_f32_16x16x32_bf16(mfr[f], xh[c], acr[jt], 0, 0, 0);
            acr[jt] = __builtin_amdgcn_mfma_f32_16x16x32_bf16(mfr[f], xl[c], acr[jt], 0, 0, 0);
            aci[jt] = __builtin_amdgcn_mfma_f32_16x16x32_bf16(mfi[f], xh[c], aci[jt], 0, 0, 0);
            aci[jt] = __builtin_amdgcn_mfma_f32_16x16x32_bf16(mfi[f], xl[c], aci[jt], 0, 0, 0);
        }
    }

    // ---- epilogue: lane holds out[row0+r][jt*16 + 4g + v], v=0..3
    float* op = out + (size_t)(row0 + r) * DIM + 4 * g;
#pragma unroll
    for (int jt = 0; jt < 4; ++jt) {
        float4 o;
        o.x = (acr[jt][0] * acr[jt][0] + aci[jt][0] * aci[jt][0]) * inv;
        o.y = (acr[jt][1] * acr[jt][1] + aci[jt][1] * aci[jt][1]) * inv;
        o.z = (acr[jt][2] * acr[jt][2] + aci[jt][2] * aci[jt][2]) * inv;
        o.w = (acr[jt][3] * acr[jt][3] + aci[jt][3] * aci[jt][3]) * inv;
        *(float4*)(op + jt * 16) = o;
    }
}

extern "C" void kernel_launch(void* const* d_in, const int* in_sizes, int n_in,
                              void* d_out, int out_size, void* d_ws, size_t ws_size,
                              hipStream_t stream) {
    const float* x = (const float*)d_in[0];
    const float* w = (const float*)d_in[1];
    float* out = (float*)d_out;
    unsigned short* Bf = (unsigned short*)d_ws;   // 16 KB fragment image
    int B = in_sizes[0] / DIM;

    hipLaunchKernelGGL(build_M, dim3(DIM), dim3(64), 0, stream, w, Bf);
    hipLaunchKernelGGL(qenc_main, dim3(B / 64), dim3(256), 0, stream, x, Bf, out);
}

// Round 17
// 17.240 us; speedup vs baseline: 1.0979x; 1.0979x over previous
//
#include <hip/hip_runtime.h>
#include <hip/hip_bf16.h>

#define NQ 6
#define DIM 64
#define NLAYERS 6

typedef __attribute__((ext_vector_type(8))) short bf16x8;
typedef __attribute__((ext_vector_type(4))) float f32x4;

// async global->LDS copy, 16B per lane, linear (dest = wave-uniform base + lane*16)
#define GLOAD_LDS16(gp, lp) \
    __builtin_amdgcn_global_load_lds((const __attribute__((address_space(1))) void*)(gp), \
                                     (__attribute__((address_space(3))) void*)(lp), 16, 0, 0)

// ---------------------------------------------------------------------------
// build_M: fused circuit matrix M = P*U5*...*P*U0*F (complex 64x64), emitted
// as MFMA fragments, single bf16 plane per component:
//   frag f = (jt*2 + chunk)*2 + plane  (0 = real, 1 = imag)
//   ushort addr = f*512 + lane16*8 + e          (16 KB total image)
//   lane16 = (j&15) + 16*((k>>3)&3), chunk = k>>5, e = k&7, jt = j>>4.
// HW trig; M bf16-rounding -> ~2e-4 on probs (validated R10+). ~0.4 us (R14).
// ---------------------------------------------------------------------------
__global__ __launch_bounds__(64) void build_M(const float* __restrict__ w,
                                              unsigned short* __restrict__ Bf) {
    const int k = blockIdx.x;    // column 0..63
    const int j = threadIdx.x;   // row/lane 0..63

    int t = (j * k) & 63;
    float sv, cv;
    __sincosf((float)t * (3.14159265358979f / 32.0f), &sv, &cv);  // exp(i*pi*t/32)
    float vr = cv * 0.125f;
    float vi = sv * 0.125f;

    int m = j;
#pragma unroll
    for (int q = 0; q < NQ; ++q) {
        int cb = 5 - q;
        int tb = 5 - ((q + 1) % NQ);
        if ((m >> cb) & 1) m ^= (1 << tb);
    }
    const int dst4 = m << 2;

#pragma unroll
    for (int l = 0; l < NLAYERS; ++l) {
#pragma unroll
        for (int q = 0; q < NQ; ++q) {
            float th = w[l * NQ + q] * 0.5f;
            float c = __cosf(th), s = __sinf(th);
            int b = 5 - q;
            float pr = __shfl_xor(vr, 1 << b);
            float pi = __shfl_xor(vi, 1 << b);
            float sgn = ((j >> b) & 1) ? s : -s;
            vr = c * vr + sgn * pr;
            vi = c * vi + sgn * pi;
        }
        vr = __int_as_float(__builtin_amdgcn_ds_permute(dst4, __float_as_int(vr)));
        vi = __int_as_float(__builtin_amdgcn_ds_permute(dst4, __float_as_int(vi)));
    }

    const int jt = j >> 4;
    const int lane16 = (j & 15) + 16 * ((k >> 3) & 3);
    const int chunk = k >> 5;
    const int e = k & 7;
    const int base = ((jt * 2 + chunk) * 2) * 512 + lane16 * 8 + e;

    __hip_bfloat16 rh = __float2bfloat16(vr);
    __hip_bfloat16 ih = __float2bfloat16(vi);
    Bf[base]       = *(unsigned short*)&rh;
    Bf[base + 512] = *(unsigned short*)&ih;
}

// ---------------------------------------------------------------------------
// qenc_main: grid 256 (1 block/CU), 512 thr = 8 waves; each wave processes
// TWO 16-row tiles sequentially (rows wid*16 + t*128), with BOTH tiles'
// x-loads issued upfront (128B/lane in flight). Tile-1 compute overlaps
// tile-0 store drain. M staged once to LDS (2 gload_lds/thread).
// ---------------------------------------------------------------------------
__global__ __launch_bounds__(512) void qenc_main(const float* __restrict__ x,
                                                 const unsigned short* __restrict__ Bf,
                                                 float* __restrict__ out) {
    __shared__ __align__(16) unsigned short sB[8192];   // 16 KB
    const int tid = threadIdx.x;
    const int lane = tid & 63;
    const int wid = tid >> 6;                 // 0..7
    const int base0 = blockIdx.x * 256 + wid * 16;      // tile 0 rows
    const int r = lane & 15;
    const int g = lane >> 4;

    // ---- issue BOTH tiles' x loads upfront
    const float* xp0 = x + (size_t)(base0 + r) * DIM + 8 * g;
    const float* xp1 = xp0 + (size_t)128 * DIM;         // tile 1 = +128 rows
    float4 a0 = *(const float4*)(xp0);
    float4 b0 = *(const float4*)(xp0 + 4);
    float4 c0 = *(const float4*)(xp0 + 32);
    float4 d0 = *(const float4*)(xp0 + 36);
    float4 a1 = *(const float4*)(xp1);
    float4 b1 = *(const float4*)(xp1 + 4);
    float4 c1 = *(const float4*)(xp1 + 32);
    float4 d1 = *(const float4*)(xp1 + 36);

    // ---- stage M to LDS (2 x 16B per thread, linear)
    GLOAD_LDS16(Bf + (size_t)tid * 8, sB + (size_t)tid * 8);
    GLOAD_LDS16(Bf + (size_t)tid * 8 + 4096, sB + (size_t)tid * 8 + 4096);

    const unsigned short* bp = sB + lane * 8;
    const f32x4 z = {0.f, 0.f, 0.f, 0.f};

    // =================== tile 0 ===================
    {
        float xf[16];
        *(float4*)(xf)      = a0;  *(float4*)(xf + 4)  = b0;
        *(float4*)(xf + 8)  = c0;  *(float4*)(xf + 12) = d0;

        float n0 = 0.f;
#pragma unroll
        for (int i = 0; i < 16; ++i) n0 = fmaf(xf[i], xf[i], n0);
        n0 += __shfl_xor(n0, 16);
        n0 += __shfl_xor(n0, 32);
        const float inv = 1.0f / n0;

        bf16x8 xh[2], xl[2];
#pragma unroll
        for (int c = 0; c < 2; ++c)
#pragma unroll
            for (int i = 0; i < 8; ++i) {
                float f = xf[c * 8 + i];
                __hip_bfloat16 hh = __float2bfloat16(f);
                __hip_bfloat16 ll = __float2bfloat16(f - __bfloat162float(hh));
                xh[c][i] = *(short*)&hh;
                xl[c][i] = *(short*)&ll;
            }

        __syncthreads();   // LDS ready (first tile only)

        f32x4 acr[4] = {z, z, z, z};
        f32x4 aci[4] = {z, z, z, z};
#pragma unroll
        for (int jt = 0; jt < 4; ++jt) {
#pragma unroll
            for (int c = 0; c < 2; ++c) {
                const unsigned short* fb = bp + ((jt * 2 + c) * 2) * 512;
                bf16x8 mr = *(const bf16x8*)(fb);
                bf16x8 mi = *(const bf16x8*)(fb + 512);
                acr[jt] = __builtin_amdgcn_mfma_f32_16x16x32_bf16(mr, xh[c], acr[jt], 0, 0, 0);
                acr[jt] = __builtin_amdgcn_mfma_f32_16x16x32_bf16(mr, xl[c], acr[jt], 0, 0, 0);
                aci[jt] = __builtin_amdgcn_mfma_f32_16x16x32_bf16(mi, xh[c], aci[jt], 0, 0, 0);
                aci[jt] = __builtin_amdgcn_mfma_f32_16x16x32_bf16(mi, xl[c], aci[jt], 0, 0, 0);
            }
        }

        float* op = out + (size_t)(base0 + r) * DIM + 4 * g;
#pragma unroll
        for (int jt = 0; jt < 4; ++jt) {
            float4 o;
            o.x = (acr[jt][0] * acr[jt][0] + aci[jt][0] * aci[jt][0]) * inv;
            o.y = (acr[jt][1] * acr[jt][1] + aci[jt][1] * aci[jt][1]) * inv;
            o.z = (acr[jt][2] * acr[jt][2] + aci[jt][2] * aci[jt][2]) * inv;
            o.w = (acr[jt][3] * acr[jt][3] + aci[jt][3] * aci[jt][3]) * inv;
            *(float4*)(op + jt * 16) = o;
        }
    }

    // =================== tile 1 ===================
    {
        float xf[16];
        *(float4*)(xf)      = a1;  *(float4*)(xf + 4)  = b1;
        *(float4*)(xf + 8)  = c1;  *(float4*)(xf + 12) = d1;

        float n0 = 0.f;
#pragma unroll
        for (int i = 0; i < 16; ++i) n0 = fmaf(xf[i], xf[i], n0);
        n0 += __shfl_xor(n0, 16);
        n0 += __shfl_xor(n0, 32);
        const float inv = 1.0f / n0;

        bf16x8 xh[2], xl[2];
#pragma unroll
        for (int c = 0; c < 2; ++c)
#pragma unroll
            for (int i = 0; i < 8; ++i) {
                float f = xf[c * 8 + i];
                __hip_bfloat16 hh = __float2bfloat16(f);
                __hip_bfloat16 ll = __float2bfloat16(f - __bfloat162float(hh));
                xh[c][i] = *(short*)&hh;
                xl[c][i] = *(short*)&ll;
            }

        f32x4 acr[4] = {z, z, z, z};
        f32x4 aci[4] = {z, z, z, z};
#pragma unroll
        for (int jt = 0; jt < 4; ++jt) {
#pragma unroll
            for (int c = 0; c < 2; ++c) {
                const unsigned short* fb = bp + ((jt * 2 + c) * 2) * 512;
                bf16x8 mr = *(const bf16x8*)(fb);
                bf16x8 mi = *(const bf16x8*)(fb + 512);
                acr[jt] = __builtin_amdgcn_mfma_f32_16x16x32_bf16(mr, xh[c], acr[jt], 0, 0, 0);
                acr[jt] = __builtin_amdgcn_mfma_f32_16x16x32_bf16(mr, xl[c], acr[jt], 0, 0, 0);
                aci[jt] = __builtin_amdgcn_mfma_f32_16x16x32_bf16(mi, xh[c], aci[jt], 0, 0, 0);
                aci[jt] = __builtin_amdgcn_mfma_f32_16x16x32_bf16(mi, xl[c], aci[jt], 0, 0, 0);
            }
        }

        float* op = out + (size_t)(base0 + 128 + r) * DIM + 4 * g;
#pragma unroll
        for (int jt = 0; jt < 4; ++jt) {
            float4 o;
            o.x = (acr[jt][0] * acr[jt][0] + aci[jt][0] * aci[jt][0]) * inv;
            o.y = (acr[jt][1] * acr[jt][1] + aci[jt][1] * aci[jt][1]) * inv;
            o.z = (acr[jt][2] * acr[jt][2] + aci[jt][2] * aci[jt][2]) * inv;
            o.w = (acr[jt][3] * acr[jt][3] + aci[jt][3] * aci[jt][3]) * inv;
            *(float4*)(op + jt * 16) = o;
        }
    }
}

extern "C" void kernel_launch(void* const* d_in, const int* in_sizes, int n_in,
                              void* d_out, int out_size, void* d_ws, size_t ws_size,
                              hipStream_t stream) {
    const float* x = (const float*)d_in[0];
    const float* w = (const float*)d_in[1];
    float* out = (float*)d_out;
    unsigned short* Bf = (unsigned short*)d_ws;   // 16 KB fragment image
    int B = in_sizes[0] / DIM;

    hipLaunchKernelGGL(build_M, dim3(DIM), dim3(64), 0, stream, w, Bf);
    hipLaunchKernelGGL(qenc_main, dim3(B / 256), dim3(512), 0, stream, x, Bf, out);
}

// Round 18
// 16.995 us; speedup vs baseline: 1.1138x; 1.0144x over previous
//
#include <hip/hip_runtime.h>
#include <hip/hip_bf16.h>

#define NQ 6
#define DIM 64
#define NLAYERS 6

typedef __attribute__((ext_vector_type(8))) short bf16x8;
typedef __attribute__((ext_vector_type(4))) float f32x4;

// async global->LDS copy, 16B per lane, linear (dest = wave-uniform base + lane*16)
#define GLOAD_LDS16(gp, lp) \
    __builtin_amdgcn_global_load_lds((const __attribute__((address_space(1))) void*)(gp), \
                                     (__attribute__((address_space(3))) void*)(lp), 16, 0, 0)

// ---------------------------------------------------------------------------
// build_M: fused circuit matrix M = P*U5*...*P*U0*F (complex 64x64), emitted
// as MFMA fragments, single bf16 plane per component:
//   frag f = (jt*2 + chunk)*2 + plane  (0 = real, 1 = imag)
//   ushort addr = f*512 + lane16*8 + e          (16 KB total image)
//   lane16 = (j&15) + 16*((k>>3)&3), chunk = k>>5, e = k&7, jt = j>>4.
// HW trig; M bf16-rounding -> ~2e-4 on probs (validated R10+). ~0.4 us (R14).
// ---------------------------------------------------------------------------
__global__ __launch_bounds__(64) void build_M(const float* __restrict__ w,
                                              unsigned short* __restrict__ Bf) {
    const int k = blockIdx.x;    // column 0..63
    const int j = threadIdx.x;   // row/lane 0..63

    int t = (j * k) & 63;
    float sv, cv;
    __sincosf((float)t * (3.14159265358979f / 32.0f), &sv, &cv);  // exp(i*pi*t/32)
    float vr = cv * 0.125f;
    float vi = sv * 0.125f;

    int m = j;
#pragma unroll
    for (int q = 0; q < NQ; ++q) {
        int cb = 5 - q;
        int tb = 5 - ((q + 1) % NQ);
        if ((m >> cb) & 1) m ^= (1 << tb);
    }
    const int dst4 = m << 2;

#pragma unroll
    for (int l = 0; l < NLAYERS; ++l) {
#pragma unroll
        for (int q = 0; q < NQ; ++q) {
            float th = w[l * NQ + q] * 0.5f;
            float c = __cosf(th), s = __sinf(th);
            int b = 5 - q;
            float pr = __shfl_xor(vr, 1 << b);
            float pi = __shfl_xor(vi, 1 << b);
            float sgn = ((j >> b) & 1) ? s : -s;
            vr = c * vr + sgn * pr;
            vi = c * vi + sgn * pi;
        }
        vr = __int_as_float(__builtin_amdgcn_ds_permute(dst4, __float_as_int(vr)));
        vi = __int_as_float(__builtin_amdgcn_ds_permute(dst4, __float_as_int(vi)));
    }

    const int jt = j >> 4;
    const int lane16 = (j & 15) + 16 * ((k >> 3) & 3);
    const int chunk = k >> 5;
    const int e = k & 7;
    const int base = ((jt * 2 + chunk) * 2) * 512 + lane16 * 8 + e;

    __hip_bfloat16 rh = __float2bfloat16(vr);
    __hip_bfloat16 ih = __float2bfloat16(vi);
    Bf[base]       = *(unsigned short*)&rh;
    Bf[base + 512] = *(unsigned short*)&ih;
}

// ---------------------------------------------------------------------------
// qenc_main: R13 geometry (ONE block per CU: 1024 thr = 16 waves, grid 256,
// 16-row tile per wave; 16 KB M staged once via global_load_lds). Streaming
// hints on BOTH sides: nontemporal x loads (avoid L2/L3 allocation -> no
// dirty-fill-line evictions) and nontemporal out stores.
// ---------------------------------------------------------------------------
__global__ __launch_bounds__(1024) void qenc_main(const float* __restrict__ x,
                                                  const unsigned short* __restrict__ Bf,
                                                  float* __restrict__ out) {
    __shared__ __align__(16) unsigned short sB[8192];   // 16 KB
    const int tid = threadIdx.x;
    const int lane = tid & 63;
    const int wid = tid >> 6;                 // 0..15
    const int row0 = blockIdx.x * 256 + wid * 16;
    const int r = lane & 15;      // batch row within tile (B-side n index)
    const int g = lane >> 4;      // k-group

    // ---- issue x loads first (nontemporal: read-once, don't allocate)
    const f32x4* xp = (const f32x4*)(x + (size_t)(row0 + r) * DIM + 8 * g);
    f32x4 va = __builtin_nontemporal_load(xp);
    f32x4 vb = __builtin_nontemporal_load(xp + 1);
    f32x4 vc = __builtin_nontemporal_load(xp + 8);
    f32x4 vd = __builtin_nontemporal_load(xp + 9);

    // ---- async stage M fragments to LDS: 1 x 16B per thread, linear
    GLOAD_LDS16(Bf + (size_t)tid * 8, sB + (size_t)tid * 8);

    float xf[16];
    *(f32x4*)(xf)      = va;  *(f32x4*)(xf + 4)  = vb;
    *(f32x4*)(xf + 8)  = vc;  *(f32x4*)(xf + 12) = vd;

    // ---- norm (reduce over the 4 lanes sharing row r)
    float n0 = 0.f;
#pragma unroll
    for (int i = 0; i < 16; ++i) n0 = fmaf(xf[i], xf[i], n0);
    n0 += __shfl_xor(n0, 16);
    n0 += __shfl_xor(n0, 32);
    const float inv = 1.0f / n0;

    // ---- hi/lo bf16 x-fragments (chunk c: k = 32c + 8g .. +7)
    bf16x8 xh[2], xl[2];
#pragma unroll
    for (int c = 0; c < 2; ++c)
#pragma unroll
        for (int i = 0; i < 8; ++i) {
            float f = xf[c * 8 + i];
            __hip_bfloat16 hh = __float2bfloat16(f);
            __hip_bfloat16 ll = __float2bfloat16(f - __bfloat162float(hh));
            xh[c][i] = *(short*)&hh;
            xl[c][i] = *(short*)&ll;
        }

    __syncthreads();   // drains vmcnt(0): staged LDS ready

    // ---- MFMA main loop: A = M fragment (LDS, single plane), B = x hi/lo
    const f32x4 z = {0.f, 0.f, 0.f, 0.f};
    f32x4 acr[4] = {z, z, z, z};
    f32x4 aci[4] = {z, z, z, z};
    const unsigned short* bp = sB + lane * 8;

#pragma unroll
    for (int jt = 0; jt < 4; ++jt) {
#pragma unroll
        for (int c = 0; c < 2; ++c) {
            const unsigned short* fb = bp + ((jt * 2 + c) * 2) * 512;
            bf16x8 mr = *(const bf16x8*)(fb);
            bf16x8 mi = *(const bf16x8*)(fb + 512);
            acr[jt] = __builtin_amdgcn_mfma_f32_16x16x32_bf16(mr, xh[c], acr[jt], 0, 0, 0);
            acr[jt] = __builtin_amdgcn_mfma_f32_16x16x32_bf16(mr, xl[c], acr[jt], 0, 0, 0);
            aci[jt] = __builtin_amdgcn_mfma_f32_16x16x32_bf16(mi, xh[c], aci[jt], 0, 0, 0);
            aci[jt] = __builtin_amdgcn_mfma_f32_16x16x32_bf16(mi, xl[c], aci[jt], 0, 0, 0);
        }
    }

    // ---- epilogue: lane holds out[row0+r][jt*16 + 4g + v], v=0..3
    float* op = out + (size_t)(row0 + r) * DIM + 4 * g;
#pragma unroll
    for (int jt = 0; jt < 4; ++jt) {
        f32x4 o;
        o[0] = (acr[jt][0] * acr[jt][0] + aci[jt][0] * aci[jt][0]) * inv;
        o[1] = (acr[jt][1] * acr[jt][1] + aci[jt][1] * aci[jt][1]) * inv;
        o[2] = (acr[jt][2] * acr[jt][2] + aci[jt][2] * aci[jt][2]) * inv;
        o[3] = (acr[jt][3] * acr[jt][3] + aci[jt][3] * aci[jt][3]) * inv;
        __builtin_nontemporal_store(o, (f32x4*)(op + jt * 16));
    }
}

extern "C" void kernel_launch(void* const* d_in, const int* in_sizes, int n_in,
                              void* d_out, int out_size, void* d_ws, size_t ws_size,
                              hipStream_t stream) {
    const float* x = (const float*)d_in[0];
    const float* w = (const float*)d_in[1];
    float* out = (float*)d_out;
    unsigned short* Bf = (unsigned short*)d_ws;   // 16 KB fragment image
    int B = in_sizes[0] / DIM;

    hipLaunchKernelGGL(build_M, dim3(DIM), dim3(64), 0, stream, w, Bf);
    hipLaunchKernelGGL(qenc_main, dim3(B / 256), dim3(1024), 0, stream, x, Bf, out);
}